// Round 6
// baseline (359.278 us; speedup 1.0000x reference)
//
#include <hip/hip_runtime.h>
#include <hip/hip_bf16.h>

// Problem constants: B=4, C=128, Cq=16, W=H=64, N=4096.
// ws layout (ushort): qT bf16 [4][4096][16] @0, kT bf16 [4][4096][16] @262144,
//                     v  bf16 [4][128][4096] @524288
// d_out: out[4][128][4096] fp32, then attention[4][4096][4096] fp32

typedef __attribute__((ext_vector_type(8))) short short8;
typedef __attribute__((ext_vector_type(16))) float float16;
typedef __attribute__((ext_vector_type(4))) float floatx4;

__device__ __forceinline__ ushort f2bf(float f) {
  union { float f; uint u; } v; v.f = f;
  return (ushort)((v.u + 0x7FFFu + ((v.u >> 16) & 1u)) >> 16);  // RNE
}

// Barrier that waits ONLY on LDS ops (lgkmcnt), not the global store stream.
// Keeps the 268MB attn write stream in flight across super-steps.
#define LDS_BARRIER()                                             \
  do {                                                            \
    __builtin_amdgcn_sched_barrier(0);                            \
    asm volatile("s_waitcnt lgkmcnt(0)" ::: "memory");            \
    __builtin_amdgcn_sched_barrier(0);                            \
    __builtin_amdgcn_s_barrier();                                 \
    __builtin_amdgcn_sched_barrier(0);                            \
  } while (0)

// ---------------- Kernel 1: QKV projections (unchanged, verified) ----------
__global__ __launch_bounds__(512, 2) void qkv_kernel(
    const float* __restrict__ x,
    const float* __restrict__ wq, const float* __restrict__ bq,
    const float* __restrict__ wk, const float* __restrict__ bk,
    const float* __restrict__ wv, const float* __restrict__ bv,
    ushort* __restrict__ qT, ushort* __restrict__ kT, ushort* __restrict__ vo) {
  __shared__ float xs[128 * 64];
  const int nt = blockIdx.x, b = blockIdx.y;
  const int n0 = nt * 64;
  const float* xb = x + (size_t)b * 524288 + n0;
  for (int idx = threadIdx.x; idx < 8192; idx += 512) {
    int c = idx >> 6, n = idx & 63;
    xs[idx] = xb[(size_t)c * 4096 + n];
  }
  __syncthreads();
  const int n = threadIdx.x & 63;
  const int og = __builtin_amdgcn_readfirstlane((int)(threadIdx.x >> 6)); // 0..7
  float acc[20];
#pragma unroll
  for (int i = 0; i < 20; i++) {
    int o = og + 8 * i;
    acc[i] = (i < 2) ? bq[o] : (i < 4) ? bk[o - 16] : bv[o - 32];
  }
#pragma unroll 4
  for (int c = 0; c < 128; c++) {
    float xr = xs[c * 64 + n];
#pragma unroll
    for (int i = 0; i < 20; i++) {
      int o = og + 8 * i;
      const float* wr = (i < 2) ? (wq + o * 128)
                      : (i < 4) ? (wk + (o - 16) * 128)
                                : (wv + (o - 32) * 128);
      acc[i] += wr[c] * xr;
    }
  }
  const size_t pos = (size_t)b * 4096 + n0 + n;
#pragma unroll
  for (int i = 0; i < 20; i++) {
    int o = og + 8 * i;
    if (i < 2)      qT[pos * 16 + o]      = f2bf(acc[i]);
    else if (i < 4) kT[pos * 16 + o - 16] = f2bf(acc[i]);
    else vo[(size_t)b * 524288 + (size_t)(o - 32) * 4096 + n0 + n] = f2bf(acc[i]);
  }
}

// ---------------- Kernel 2: fused energy + softmax + attn + PV -------------
// R0-verified structure. Change this round: p-values are staged fp32 in LDS
// (Pf[32][256]) during the E/exp phase instead of being scatter-stored 4B at
// a time; after the barrier each wave emits the super-step's 32x(sl*64) tile
// as contiguous 1KB dwordx4 row-bursts (8x larger bursts), issued before the
// PV MFMAs so the write stream drains under compute.
__global__ __launch_bounds__(256, 2) void fused_attn_kernel(
    const ushort* __restrict__ qT, const ushort* __restrict__ kT,
    const ushort* __restrict__ vws, const float* __restrict__ x,
    const float* __restrict__ g,
    float* __restrict__ attn, float* __restrict__ out) {
  __shared__ __align__(16) ushort Pt[4][32 * 72];
  __shared__ __align__(16) float Pf[32 * 256];
  __shared__ __align__(16) float red[32][4];
  const int bx = blockIdx.x;            // 0..511
  const int b = bx & 3;
  const int v_ = bx >> 2;               // 0..127
  const int half = v_ & 1;
  const int u = v_ >> 1;                // 0..63
  const int rb = (u < 32) ? u : 95 - u; // CU-mate load balancing
  const int S = rb + 1;
  const int lane = threadIdx.x & 63;
  const int w = __builtin_amdgcn_readfirstlane((int)(threadIdx.x >> 6));
  const int nblk = rb * 64 + half * 32;
  const int l31 = lane & 31;
  const int h = lane >> 5;
  const int hk = h * 8;
  const ushort* qb = qT + (size_t)b * 65536;
  const ushort* kb = kT + (size_t)b * 65536;
  const ushort* vp = vws + (size_t)b * 524288;
  float* ab = attn + (size_t)b * 16777216;

  // q A-fragment for this block's 32 rows: A[n=l31][d=hk..hk+7] — 4 VGPRs.
  const short8 qa = *(const short8*)(qb + (size_t)(nblk + l31) * 16 + hk);

  float16 zero16;
#pragma unroll
  for (int i = 0; i < 16; i++) zero16[i] = 0.f;

  // ---- Phase 1: denominators ----
  float sume[16];
#pragma unroll
  for (int i = 0; i < 16; i++) sume[i] = 0.f;
  for (int s = w; s < S; s += 4) {
    const int m0 = s * 64;
#pragma unroll
    for (int mh = 0; mh < 2; mh++) {
      short8 kf = *(const short8*)(kb + (size_t)(m0 + mh * 32 + l31) * 16 + hk);
      float16 e = __builtin_amdgcn_mfma_f32_32x32x16_bf16(qa, kf, zero16, 0, 0, 0);
#pragma unroll
      for (int r = 0; r < 16; r++) sume[r] += __expf(e[r]);
    }
  }
#pragma unroll
  for (int r = 0; r < 16; r++) {
#pragma unroll
    for (int off = 1; off <= 16; off <<= 1)
      sume[r] += __shfl_xor(sume[r], off, 64);  // sum over 32 cols (l31 group)
  }
  if (l31 == 0) {
#pragma unroll
    for (int r = 0; r < 16; r++) {
      int row = (r & 3) + 8 * (r >> 2) + 4 * h;
      red[row][w] = sume[r];
    }
  }
  __syncthreads();
  float inv[16];
#pragma unroll
  for (int r = 0; r < 16; r++) {
    int row = (r & 3) + 8 * (r >> 2) + 4 * h;
    float4 p4 = *(const float4*)&red[row][0];
    inv[r] = 1.0f / (p4.x + p4.y + p4.z + p4.w);
  }

  // ---- Phase 2: attn write (LDS-staged bursts) + PV accumulate ----
  float16 acc = zero16;
  for (int s0 = 0; s0 < S; s0 += 4) {
    const int sl = (S - s0 < 4) ? (S - s0) : 4;
    if (w < sl) {
      const int m0 = (s0 + w) * 64;
      ushort* Pb = &Pt[w][0];
      float* Pc = &Pf[w * 64];
#pragma unroll
      for (int mh = 0; mh < 2; mh++) {
        short8 kf = *(const short8*)(kb + (size_t)(m0 + mh * 32 + l31) * 16 + hk);
        float16 e = __builtin_amdgcn_mfma_f32_32x32x16_bf16(qa, kf, zero16, 0, 0, 0);
#pragma unroll
        for (int r = 0; r < 16; r++) {
          int row = (r & 3) + 8 * (r >> 2) + 4 * h;
          float p = __expf(e[r]) * inv[r];
          Pc[row * 256 + mh * 32 + l31] = p;          // fp32 stage (LDS)
          Pb[row * 72 + mh * 32 + l31] = f2bf(p);     // bf16 for PV
        }
      }
    }
    LDS_BARRIER();   // LDS handoff only; global stores stay in flight

    // Burst write-out: wave w emits rows w*8..w*8+7, 1KB contiguous per inst.
    {
      const int cols4 = sl * 16;           // float4 count per row
      if (lane < cols4) {
#pragma unroll
        for (int rr = 0; rr < 8; rr++) {
          int row = w * 8 + rr;
          floatx4 val = *(const floatx4*)&Pf[row * 256 + lane * 4];
          *(floatx4*)(ab + (size_t)(nblk + row) * 4096 + s0 * 64 + lane * 4) = val;
        }
      }
    }

    for (int ss = 0; ss < sl; ss++) {
      const int m0 = (s0 + ss) * 64;
      const ushort* vrow = vp + (size_t)(w * 32 + l31) * 4096 + m0 + hk;
      const ushort* Pr = &Pt[ss][l31 * 72 + hk];
#pragma unroll
      for (int kk = 0; kk < 4; kk++) {
        short8 a  = *(const short8*)(vrow + kk * 16);
        short8 bf = *(const short8*)(Pr + kk * 16);
        acc = __builtin_amdgcn_mfma_f32_32x32x16_bf16(a, bf, acc, 0, 0, 0);
      }
    }
    LDS_BARRIER();   // protects Pt/Pf overwrite; no vmcnt drain
  }

  // ---- Epilogue: zero-fill masked attn region (wave w: rows w*8..w*8+7) ----
  const int M = S * 64;
  const int Z4 = (4096 - M) >> 2;
  const floatx4 z = {0.f, 0.f, 0.f, 0.f};
#pragma unroll
  for (int r = 0; r < 8; r++) {
    floatx4* dst = (floatx4*)(ab + (size_t)(nblk + w * 8 + r) * 4096 + M);
    for (int i4 = lane; i4 < Z4; i4 += 64) dst[i4] = z;
  }

  // ---- Epilogue: out = gamma * acc + x ----
  const float gamma = g[0];
#pragma unroll
  for (int reg = 0; reg < 16; reg++) {
    int row = (reg & 3) + 8 * (reg >> 2) + 4 * h;  // C/D row map
    int c = w * 32 + row;
    int n = nblk + l31;                            // C/D col = lane&31
    size_t off = (size_t)b * 524288 + (size_t)c * 4096 + n;
    out[off] = gamma * acc[reg] + x[off];
  }
}

extern "C" void kernel_launch(void* const* d_in, const int* in_sizes, int n_in,
                              void* d_out, int out_size, void* d_ws, size_t ws_size,
                              hipStream_t stream) {
  const float* x  = (const float*)d_in[0];
  const float* wq = (const float*)d_in[1];
  const float* bq = (const float*)d_in[2];
  const float* wk = (const float*)d_in[3];
  const float* bk = (const float*)d_in[4];
  const float* wv = (const float*)d_in[5];
  const float* bv = (const float*)d_in[6];
  const float* gm = (const float*)d_in[7];
  float* out  = (float*)d_out;
  float* attn = out + 2097152;            // output 1: attention [4][4096][4096]
  ushort* qTw = (ushort*)d_ws;            // bf16 [4][4096][16]
  ushort* kTw = qTw + 262144;             // bf16 [4][4096][16]
  ushort* vws = qTw + 524288;             // bf16 [4][128][4096]

  qkv_kernel<<<dim3(64, 4), 512, 0, stream>>>(x, wq, bq, wk, bk, wv, bv, qTw, kTw, vws);
  fused_attn_kernel<<<dim3(512), 256, 0, stream>>>(qTw, kTw, vws, x, gm, attn, out);
}

// Round 7
// 347.490 us; speedup vs baseline: 1.0339x; 1.0339x over previous
//
#include <hip/hip_runtime.h>
#include <hip/hip_bf16.h>

// Problem constants: B=4, C=128, Cq=16, W=H=64, N=4096.
// ws layout (ushort): qT bf16 [4][4096][16] @0, kT bf16 [4][4096][16] @262144,
//                     v  bf16 [4][128][4096] @524288
// d_out: out[4][128][4096] fp32, then attention[4][4096][4096] fp32

typedef __attribute__((ext_vector_type(8))) short short8;
typedef __attribute__((ext_vector_type(16))) float float16;
typedef __attribute__((ext_vector_type(4))) float floatx4;

__device__ __forceinline__ ushort f2bf(float f) {
  union { float f; uint u; } v; v.f = f;
  return (ushort)((v.u + 0x7FFFu + ((v.u >> 16) & 1u)) >> 16);  // RNE
}

// Barrier that waits ONLY on LDS ops (lgkmcnt), not the global store stream.
#define LDS_BARRIER()                                             \
  do {                                                            \
    __builtin_amdgcn_sched_barrier(0);                            \
    asm volatile("s_waitcnt lgkmcnt(0)" ::: "memory");            \
    __builtin_amdgcn_sched_barrier(0);                            \
    __builtin_amdgcn_s_barrier();                                 \
    __builtin_amdgcn_sched_barrier(0);                            \
  } while (0)

// ---------------- Kernel 1: QKV projections (unchanged, verified) ----------
__global__ __launch_bounds__(512, 2) void qkv_kernel(
    const float* __restrict__ x,
    const float* __restrict__ wq, const float* __restrict__ bq,
    const float* __restrict__ wk, const float* __restrict__ bk,
    const float* __restrict__ wv, const float* __restrict__ bv,
    ushort* __restrict__ qT, ushort* __restrict__ kT, ushort* __restrict__ vo) {
  __shared__ float xs[128 * 64];
  const int nt = blockIdx.x, b = blockIdx.y;
  const int n0 = nt * 64;
  const float* xb = x + (size_t)b * 524288 + n0;
  for (int idx = threadIdx.x; idx < 8192; idx += 512) {
    int c = idx >> 6, n = idx & 63;
    xs[idx] = xb[(size_t)c * 4096 + n];
  }
  __syncthreads();
  const int n = threadIdx.x & 63;
  const int og = __builtin_amdgcn_readfirstlane((int)(threadIdx.x >> 6)); // 0..7
  float acc[20];
#pragma unroll
  for (int i = 0; i < 20; i++) {
    int o = og + 8 * i;
    acc[i] = (i < 2) ? bq[o] : (i < 4) ? bk[o - 16] : bv[o - 32];
  }
#pragma unroll 4
  for (int c = 0; c < 128; c++) {
    float xr = xs[c * 64 + n];
#pragma unroll
    for (int i = 0; i < 20; i++) {
      int o = og + 8 * i;
      const float* wr = (i < 2) ? (wq + o * 128)
                      : (i < 4) ? (wk + (o - 16) * 128)
                                : (wv + (o - 32) * 128);
      acc[i] += wr[c] * xr;
    }
  }
  const size_t pos = (size_t)b * 4096 + n0 + n;
#pragma unroll
  for (int i = 0; i < 20; i++) {
    int o = og + 8 * i;
    if (i < 2)      qT[pos * 16 + o]      = f2bf(acc[i]);
    else if (i < 4) kT[pos * 16 + o - 16] = f2bf(acc[i]);
    else vo[(size_t)b * 524288 + (size_t)(o - 32) * 4096 + n0 + n] = f2bf(acc[i]);
  }
}

// ---------------- Kernel 2: fused energy + softmax + attn + PV -------------
// 8-WAVE version (512 thr/block, 512 blocks, 2 blocks/CU = 4 waves/SIMD).
// Halves every serial chain vs the 4-wave kernel: phase 1 strides strips by
// 8; phase 2 super-steps cover 8 strips (E: wave w -> strip s0+w; PV: wave
// (q,hh)=(w&3,w>>2) accumulates strips of parity hh for c-quadrant q; the
// two half-accumulators are combined through LDS in the epilogue).
__global__ __launch_bounds__(512, 4) void fused_attn_kernel(
    const ushort* __restrict__ qT, const ushort* __restrict__ kT,
    const ushort* __restrict__ vws, const float* __restrict__ x,
    const float* __restrict__ g,
    float* __restrict__ attn, float* __restrict__ out) {
  __shared__ __align__(16) ushort Pt[8][32 * 72];   // 36,864 B (also acc scratch)
  __shared__ __align__(16) float red[32][8];        // 1 KB
  const int bx = blockIdx.x;            // 0..511
  const int b = bx & 3;
  const int v_ = bx >> 2;               // 0..127
  const int half = v_ & 1;
  const int u = v_ >> 1;                // 0..63
  const int rb = (u < 32) ? u : 95 - u; // CU-mate load balancing (pair sums 65)
  const int S = rb + 1;
  const int lane = threadIdx.x & 63;
  const int w = __builtin_amdgcn_readfirstlane((int)(threadIdx.x >> 6)); // 0..7
  const int q = w & 3;                  // PV c-quadrant
  const int hh = w >> 2;                // PV strip parity
  const int nblk = rb * 64 + half * 32;
  const int l31 = lane & 31;
  const int h = lane >> 5;
  const int hk = h * 8;
  const ushort* qb = qT + (size_t)b * 65536;
  const ushort* kb = kT + (size_t)b * 65536;
  const ushort* vp = vws + (size_t)b * 524288;
  float* ab = attn + (size_t)b * 16777216;

  // q A-fragment for this block's 32 rows: A[n=l31][d=hk..hk+7] — 4 VGPRs.
  const short8 qa = *(const short8*)(qb + (size_t)(nblk + l31) * 16 + hk);

  float16 zero16;
#pragma unroll
  for (int i = 0; i < 16; i++) zero16[i] = 0.f;

  // ---- Phase 1: denominators (8-way strip parallel) ----
  float sume[16];
#pragma unroll
  for (int i = 0; i < 16; i++) sume[i] = 0.f;
  for (int s = w; s < S; s += 8) {
    const int m0 = s * 64;
#pragma unroll
    for (int mh = 0; mh < 2; mh++) {
      short8 kf = *(const short8*)(kb + (size_t)(m0 + mh * 32 + l31) * 16 + hk);
      float16 e = __builtin_amdgcn_mfma_f32_32x32x16_bf16(qa, kf, zero16, 0, 0, 0);
#pragma unroll
      for (int r = 0; r < 16; r++) sume[r] += __expf(e[r]);
    }
  }
#pragma unroll
  for (int r = 0; r < 16; r++) {
#pragma unroll
    for (int off = 1; off <= 16; off <<= 1)
      sume[r] += __shfl_xor(sume[r], off, 64);  // sum over 32 cols (l31 group)
  }
  if (l31 == 0) {
#pragma unroll
    for (int r = 0; r < 16; r++) {
      int row = (r & 3) + 8 * (r >> 2) + 4 * h;
      red[row][w] = sume[r];
    }
  }
  __syncthreads();
  float inv[16];
#pragma unroll
  for (int r = 0; r < 16; r++) {
    int row = (r & 3) + 8 * (r >> 2) + 4 * h;
    const float* pr = &red[row][0];
    float t = ((pr[0] + pr[1]) + (pr[2] + pr[3])) +
              ((pr[4] + pr[5]) + (pr[6] + pr[7]));
    inv[r] = 1.0f / t;
  }

  // ---- Phase 2: attn write + PV accumulate (8 strips / super-step) ----
  float16 acc = zero16;
  for (int s0 = 0; s0 < S; s0 += 8) {
    const int sl = (S - s0 < 8) ? (S - s0) : 8;
    if (w < sl) {
      const int m0 = (s0 + w) * 64;
      ushort* Pb = &Pt[w][0];
#pragma unroll
      for (int mh = 0; mh < 2; mh++) {
        short8 kf = *(const short8*)(kb + (size_t)(m0 + mh * 32 + l31) * 16 + hk);
        float16 e = __builtin_amdgcn_mfma_f32_32x32x16_bf16(qa, kf, zero16, 0, 0, 0);
#pragma unroll
        for (int r = 0; r < 16; r++) {
          int row = (r & 3) + 8 * (r >> 2) + 4 * h;
          float p = __expf(e[r]) * inv[r];
          ab[(size_t)(nblk + row) * 4096 + m0 + mh * 32 + l31] = p;
          Pb[row * 72 + mh * 32 + l31] = f2bf(p);
        }
      }
    }
    LDS_BARRIER();   // LDS handoff only; attn stores stay in flight
    for (int ss = hh; ss < sl; ss += 2) {
      const int m0 = (s0 + ss) * 64;
      const ushort* vrow = vp + (size_t)(q * 32 + l31) * 4096 + m0 + hk;
      const ushort* Pr = &Pt[ss][l31 * 72 + hk];
#pragma unroll
      for (int kk = 0; kk < 4; kk++) {
        short8 a  = *(const short8*)(vrow + kk * 16);
        short8 bf = *(const short8*)(Pr + kk * 16);
        acc = __builtin_amdgcn_mfma_f32_32x32x16_bf16(a, bf, acc, 0, 0, 0);
      }
    }
    LDS_BARRIER();   // protects Pt overwrite; no vmcnt drain
  }

  // ---- Combine acc halves (hh=1 -> LDS -> hh=0) ----
  float* accx = (float*)&Pt[0][0];   // [16][256] floats = 16 KB, stride-1/lane
  if (hh == 1) {
#pragma unroll
    for (int reg = 0; reg < 16; reg++)
      accx[reg * 256 + q * 64 + lane] = acc[reg];
  }
  __syncthreads();
  if (hh == 0) {
#pragma unroll
    for (int reg = 0; reg < 16; reg++)
      acc[reg] += accx[reg * 256 + q * 64 + lane];
  }

  // ---- Epilogue: zero-fill masked attn region (wave w: rows w*4..w*4+3) ----
  const int M = S * 64;
  const int Z4 = (4096 - M) >> 2;
  const floatx4 z = {0.f, 0.f, 0.f, 0.f};
#pragma unroll
  for (int r = 0; r < 4; r++) {
    floatx4* dst = (floatx4*)(ab + (size_t)(nblk + w * 4 + r) * 4096 + M);
    for (int i4 = lane; i4 < Z4; i4 += 64) dst[i4] = z;
  }

  // ---- Epilogue: out = gamma * acc + x (hh=0 waves only) ----
  if (hh == 0) {
    const float gamma = g[0];
#pragma unroll
    for (int reg = 0; reg < 16; reg++) {
      int row = (reg & 3) + 8 * (reg >> 2) + 4 * h;  // C/D row map
      int c = q * 32 + row;
      int n = nblk + l31;                            // C/D col = lane&31
      size_t off = (size_t)b * 524288 + (size_t)c * 4096 + n;
      out[off] = gamma * acc[reg] + x[off];
    }
  }
}

extern "C" void kernel_launch(void* const* d_in, const int* in_sizes, int n_in,
                              void* d_out, int out_size, void* d_ws, size_t ws_size,
                              hipStream_t stream) {
  const float* x  = (const float*)d_in[0];
  const float* wq = (const float*)d_in[1];
  const float* bq = (const float*)d_in[2];
  const float* wk = (const float*)d_in[3];
  const float* bk = (const float*)d_in[4];
  const float* wv = (const float*)d_in[5];
  const float* bv = (const float*)d_in[6];
  const float* gm = (const float*)d_in[7];
  float* out  = (float*)d_out;
  float* attn = out + 2097152;            // output 1: attention [4][4096][4096]
  ushort* qTw = (ushort*)d_ws;            // bf16 [4][4096][16]
  ushort* kTw = qTw + 262144;             // bf16 [4][4096][16]
  ushort* vws = qTw + 524288;             // bf16 [4][128][4096]

  qkv_kernel<<<dim3(64, 4), 512, 0, stream>>>(x, wq, bq, wk, bk, wv, bv, qTw, kTw, vws);
  fused_attn_kernel<<<dim3(512), 512, 0, stream>>>(qTw, kTw, vws, x, gm, attn, out);
}